// Round 13
// baseline (60.434 us; speedup 1.0000x reference)
//
#include <hip/hip_runtime.h>

typedef unsigned int   u32;
typedef unsigned short u16;
typedef _Float16       f16;

using f16x8  = __attribute__((ext_vector_type(8)))  _Float16;
using f16x4  = __attribute__((ext_vector_type(4)))  _Float16;
using f32x16 = __attribute__((ext_vector_type(16))) float;

#define LLDS16(G, L) __builtin_amdgcn_global_load_lds( \
  (const __attribute__((address_space(1))) u32*)(G), \
  (__attribute__((address_space(3))) u32*)(L), 16, 0, 0)

#define WAITV(N) { asm volatile("s_waitcnt vmcnt(" #N ")" ::: "memory"); \
                   __builtin_amdgcn_sched_barrier(0); }
#define FENCE_BAR() { asm volatile("s_waitcnt lgkmcnt(0)" ::: "memory"); \
                      __builtin_amdgcn_sched_barrier(0); \
                      __builtin_amdgcn_s_barrier(); \
                      __builtin_amdgcn_sched_barrier(0); }
#define BAR() { __builtin_amdgcn_s_barrier(); __builtin_amdgcn_sched_barrier(0); }
#define KEEP(x) asm volatile("" : "+v"(x))

// ---- merged prep: [bid<2560] x transpose+sums; [else] W0/W1 k-panel ----
__global__ __launch_bounds__(256)
void prep(const float* __restrict__ x,
          const float* __restrict__ W0, const float* __restrict__ W1,
          f16* __restrict__ xt, f16* __restrict__ W0p, f16* __restrict__ W1p,
          float* __restrict__ out){
  __shared__ char shm[33920];
  const int tid = threadIdx.x;
  if (blockIdx.x < 2560){
    float (*tile)[33] = (float(*)[33])shm;
    const int r0 = blockIdx.x << 5;
    const int c  = tid & 31;
    const int rp = tid >> 5;
#pragma unroll
    for (int p = 0; p < 4; ++p){
      const int r = (p << 3) + rp;
      float v = x[(size_t)(r0 + r) * 32 + c];
      tile[r][c] = v;
      float s = v;
#pragma unroll
      for (int off = 16; off > 0; off >>= 1) s += __shfl_xor(s, off, 32);
      if (c == 0){
        const int row = r0 + r;            // = b*40 + f
        out[(size_t)(row / 40) * 168 + (row % 40)] = s;
      }
    }
    __syncthreads();
#pragma unroll
    for (int p = 0; p < 4; ++p){
      const int dd = (p << 3) + rp;
      xt[(size_t)dd * 81920 + r0 + c] = (f16)tile[c][dd];
    }
  } else {
    u16* t = (u16*)shm;
    int kb = blockIdx.x - 2560;
    const float* in; f16* outp; int K;
    if (kb < 200){ in = W0; outp = W0p; K = 1600; }
    else         { kb -= 200; in = W1; outp = W1p; K = 2560; }
    const int kbase = kb << 3;
#pragma unroll 4
    for (int i = 0; i < 64; ++i){
      const int idx = tid + (i << 8);
      const int o   = idx >> 8;
      const int rem = idx & 255;
      const int e   = rem >> 5;
      const int dd  = rem & 31;
      const float v = in[(size_t)o * (K * 32) + (size_t)(kbase + e) * 32 + dd];
      union { f16 h; u16 u; } cv; cv.h = (f16)v;
      t[dd * 530 + o * 8 + e] = cv.u;
    }
    __syncthreads();
    const u32* t32 = (const u32*)t;
    u32* o32 = (u32*)outp;
    const int obase = kb << 8;
#pragma unroll 4
    for (int i = 0; i < 32; ++i){
      const int idx = tid + (i << 8);
      const int dd  = idx >> 8;
      const int rem = idx & 255;
      o32[(size_t)dd * (K * 32) + obase + rem] = t32[dd * 265 + rem];
    }
  }
}

// ---- fused CIN: 32x32x16, 64-row waves, TRIPLE-buffered B, 1 barrier/tile ----
// Block: 128 rows x 64 cols x one d, 4 waves (2 rowhalves x 2 colhalves).
// BK=160; 26 tiles (10 W0 + 16 W1); 2-deep prefetch, counted vmcnt(5).
// Per-tile: WAITV -> BAR -> ISSUE(t+2) -> COMP(t).  4 indep acc chains.
__global__ __launch_bounds__(256, 2)
void cin_fused(const f16* __restrict__ xt,     // [32][2048*40] f16
               const f16* __restrict__ W0p,    // [32][200][64][8] f16
               const f16* __restrict__ W1p,    // [32][320][64][8] f16
               const float* __restrict__ b0v, const float* __restrict__ b1v,
               f16* __restrict__ x1s,          // [2048][32][64] f16
               f16* __restrict__ y2s){         // [2048][32][64] f16
  constexpr int XOFF = 61440;           // after 3 x 20KB B bufs; x0/x1/y overlay
  constexpr int X0MS = 32 * 96;         // strip stride (x0)
  constexpr int X1MS = 32 * 144;        // strip stride (x1)

  const int bid = blockIdx.x;
  const int d   = ((bid & 7) << 2) | ((bid >> 3) & 3);   // XCD-local d groups
  const int b0  = (bid >> 5) << 7;      // 16 b-tiles of 128 rows
  const int tid = threadIdx.x;
  const int wv  = tid >> 6;
  const int wr  = wv >> 1;              // row half (64 rows)
  const int wc  = wv & 1;               // col half (32 cols)
  const int l   = tid & 63;
  const int hi  = l >> 5;               // k-run half
  const int lr  = l & 31;

  __shared__ char smem[79872];

  const f16* gW0 = W0p + (size_t)d * 102400;
  const f16* gW1 = W1p + (size_t)d * 163840;

  // W tile = 20480B = 20 x 1KB chunks; wave wv loads chunks {wv+4j}, 5 each.
#define ISSUE(I, BUF) do { \
    const f16* src_ = ((I) < 10) ? (gW0 + (size_t)(I) * 10240) \
                                 : (gW1 + (size_t)((I) - 10) * 10240); \
    const f16* gt_ = src_ + l * 8; \
    char* lb_ = smem + (BUF) * 20480; \
    _Pragma("unroll") \
    for (int j_ = 0; j_ < 5; ++j_) \
      LLDS16(gt_ + (size_t)(wv + 4 * j_) * 512, lb_ + (wv + 4 * j_) * 1024); \
  } while (0)

  ISSUE(0, 0);
  ISSUE(1, 1);

  { // stage x0 tile: 128 rows * 80B -> stride 96B
    const uint4* src = (const uint4*)(xt + (size_t)d * 81920 + (size_t)b0 * 40);
#pragma unroll
    for (int it = 0; it < 3; ++it){
      const int idx = tid + (it << 8);
      if (idx < 640){
        const int r = idx / 5, c = idx - r * 5;
        *(uint4*)(smem + XOFF + r * 96 + c * 16) = src[idx];
      }
    }
  }
  __syncthreads();                      // drains vmcnt: tiles 0,1 + x0 landed

  const char* x0r = smem + XOFF + ((wr << 6) + lr) * 96;
  const char* x1r = smem + XOFF + ((wr << 6) + lr) * 144;
  const int   col = (wc << 5) + lr;
  const float bv1 = b0v[col];
  const float bv2 = b1v[col];

  // sl[m][s] = x0 f-block (s+hi)%5 of strip-m row (pinned in VGPRs)
  f16x8 sl[2][5];
#pragma unroll
  for (int m = 0; m < 2; ++m){
    const char* xe = x0r + m * X0MS + hi * 16;
#pragma unroll
    for (int t = 0; t < 4; ++t) sl[m][t] = *(const f16x8*)(xe + t * 16);
    sl[m][4] = *(const f16x8*)(x0r + m * X0MS + (hi ? 0 : 64));
  }
  KEEP(sl[0][0]); KEEP(sl[0][1]); KEEP(sl[0][2]); KEEP(sl[0][3]); KEEP(sl[0][4]);
  KEEP(sl[1][0]); KEEP(sl[1][1]); KEEP(sl[1][2]); KEEP(sl[1][3]); KEEP(sl[1][4]);

  const f32x16 fz = {0,0,0,0,0,0,0,0,0,0,0,0,0,0,0,0};
  f32x16 acc0a = fz, acc0b = fz, acc1a = fz, acc1b = fz;   // 4 indep chains

  const int vb = (hi << 10) + (wc << 9) + (lr << 4);

  // r8 = si*4 + 2p + hi; slot = (si*4+2p)%5 (hi-rotated sl); h-elem tables
  static constexpr int J0[5]  = {0, 4, 3, 2, 1};
  static constexpr int H0[5]  = {0, 0, 1, 2, 3};
  static constexpr int H0b[5] = {0, 1, 1, 2, 3};
  static constexpr int S0[5]  = {0, 1, 0, 0, 0};
  static constexpr int J2[5]  = {2, 1, 0, 4, 3};
  static constexpr int H2[5]  = {0, 1, 2, 2, 3};
  static constexpr int H2b[5] = {0, 1, 2, 3, 3};
  static constexpr int S2[5]  = {0, 0, 0, 1, 0};

#define COMP(BB) do { \
  __builtin_amdgcn_s_setprio(1); \
  _Pragma("unroll") \
  for (int si = 0; si < 5; ++si){ \
    const f16x8 bf0 = *(const f16x8*)((BB) + vb + si * 4096); \
    const f16x8 bf2 = *(const f16x8*)((BB) + vb + si * 4096 + 2048); \
    const f16 xa00 = (S0[si] && hi) ? xh0[H0b[si]] : xh0[H0[si]]; \
    const f16 xa01 = (S0[si] && hi) ? xh1[H0b[si]] : xh1[H0[si]]; \
    const f16 xa20 = (S2[si] && hi) ? xh0[H2b[si]] : xh0[H2[si]]; \
    const f16 xa21 = (S2[si] && hi) ? xh1[H2b[si]] : xh1[H2[si]]; \
    acc0a = __builtin_amdgcn_mfma_f32_32x32x16_f16(sl[0][J0[si]] * xa00, bf0, acc0a, 0, 0, 0); \
    acc1a = __builtin_amdgcn_mfma_f32_32x32x16_f16(sl[1][J0[si]] * xa01, bf0, acc1a, 0, 0, 0); \
    acc0b = __builtin_amdgcn_mfma_f32_32x32x16_f16(sl[0][J2[si]] * xa20, bf2, acc0b, 0, 0, 0); \
    acc1b = __builtin_amdgcn_mfma_f32_32x32x16_f16(sl[1][J2[si]] * xa21, bf2, acc1b, 0, 0, 0); \
  } \
  __builtin_amdgcn_s_setprio(0); \
} while (0)

  int cur = 0, ib = 2;

  // ---------------- phase 1: xk = x0, tiles 0..9 ----------------
  for (int t = 0; t < 10; ++t){
    if (t > 0){ WAITV(5); BAR(); }      // tile t landed (all waves after BAR)
    ISSUE(t + 2, ib);                   // tiles 2..11 (10,11 are W1 tiles 0,1)
    const f16x4 xh0 = *(const f16x4*)(x0r + t * 8);
    const f16x4 xh1 = *(const f16x4*)(x0r + X0MS + t * 8);
    COMP(smem + cur * 20480);
    cur = cur + 1; if (cur == 3) cur = 0;
    ib  = ib + 1;  if (ib == 3)  ib = 0;
  }

  // ---- epilogue 1: x1 -> LDS (overlay x0), coalesced partial store ----
  {
    FENCE_BAR();                        // all waves done COMP(9)/x0 reads
    u16* x1w = (u16*)(smem + XOFF);
#pragma unroll
    for (int m = 0; m < 2; ++m)
#pragma unroll
      for (int reg = 0; reg < 16; ++reg){
        const int row = (wr << 6) + (m << 5) + (reg & 3) + ((reg >> 2) << 3) + (hi << 2);
        float v = (m ? acc1a[reg] + acc1b[reg] : acc0a[reg] + acc0b[reg]) + bv1;
        v = v > 0.f ? v : 0.f;
        union { f16 h; u16 u; } cv; cv.h = (f16)v;
        x1w[row * 72 + col] = cv.u;
      }
    acc0a = fz; acc0b = fz; acc1a = fz; acc1b = fz;
    FENCE_BAR();                        // x1 tile visible to all waves
#pragma unroll
    for (int it = 0; it < 4; ++it){     // 4 global stores (counted in vmcnt)
      const int u   = tid + (it << 8);
      const int row = u >> 3, ch = u & 7;
      const f16x8 vv = *(const f16x8*)((const char*)x1w + row * 144 + ch * 16);
      *(f16x8*)(x1s + (size_t)(b0 + row) * 2048 + d * 64 + ch * 8) = vv;
    }
  }

  // ---------------- phase 2: xk = x1 (LDS), tiles 10..25 ----------------
  for (int t2 = 0; t2 < 16; ++t2){
    if (t2 < 2)       { WAITV(9); }     // tile landed past 4 stores + 5 chunks
    else if (t2 < 15) { WAITV(5); }
    else              { WAITV(0); }
    BAR();
    if (t2 + 2 < 16) ISSUE(12 + t2, ib);
    const f16x4 xh0 = *(const f16x4*)(x1r + t2 * 8);
    const f16x4 xh1 = *(const f16x4*)(x1r + X1MS + t2 * 8);
    COMP(smem + cur * 20480);
    cur = cur + 1; if (cur == 3) cur = 0;
    ib  = ib + 1;  if (ib == 3)  ib = 0;
  }

  // ---- epilogue 2: y2 -> LDS (overlay x1) -> coalesced partial store ----
  {
    FENCE_BAR();                        // all waves done phase-2 x1 reads
    u16* yw = (u16*)(smem + XOFF);
#pragma unroll
    for (int m = 0; m < 2; ++m)
#pragma unroll
      for (int reg = 0; reg < 16; ++reg){
        const int row = (wr << 6) + (m << 5) + (reg & 3) + ((reg >> 2) << 3) + (hi << 2);
        float v = (m ? acc1a[reg] + acc1b[reg] : acc0a[reg] + acc0b[reg]) + bv2;
        v = v > 0.f ? v : 0.f;
        union { f16 h; u16 u; } cv; cv.h = (f16)v;
        yw[row * 72 + col] = cv.u;
      }
    FENCE_BAR();
#pragma unroll
    for (int it = 0; it < 4; ++it){
      const int u   = tid + (it << 8);
      const int row = u >> 3, ch = u & 7;
      const f16x8 vv = *(const f16x8*)((const char*)yw + row * 144 + ch * 16);
      *(f16x8*)(y2s + (size_t)(b0 + row) * 2048 + d * 64 + ch * 8) = vv;
    }
  }
#undef ISSUE
#undef COMP
}

// ------- final: out[b, 40:168] = sum_d concat(x1, y2), coalesced reads -------
__global__ __launch_bounds__(128)
void finalize(const f16* __restrict__ x1s, const f16* __restrict__ y2s,
              float* __restrict__ out){
  const int b = blockIdx.x;
  const int t = threadIdx.x;
  if (t < 64){
    float s = 0.f;
#pragma unroll
    for (int d = 0; d < 32; ++d) s += (float)x1s[(size_t)b * 2048 + d * 64 + t];
    out[(size_t)b * 168 + 40 + t] = s;
  } else {
    const int o = t - 64;
    float s = 0.f;
#pragma unroll
    for (int d = 0; d < 32; ++d) s += (float)y2s[(size_t)b * 2048 + d * 64 + o];
    out[(size_t)b * 168 + 104 + o] = s;
  }
}

extern "C" void kernel_launch(void* const* d_in, const int* in_sizes, int n_in,
                              void* d_out, int out_size, void* d_ws, size_t ws_size,
                              hipStream_t stream){
  const float* x   = (const float*)d_in[0];
  const float* W0  = (const float*)d_in[1];
  const float* b0v = (const float*)d_in[2];
  const float* W1  = (const float*)d_in[3];
  const float* b1v = (const float*)d_in[4];
  float* out = (float*)d_out;

  char* ws = (char*)d_ws;
  f16* xt  = (f16*)(ws + 0);            // 32*2048*40*2  =  5,242,880
  f16* W0p = (f16*)(ws + 5242880);      // 32*64*1600*2  =  6,553,600
  f16* W1p = (f16*)(ws + 11796480);     // 32*64*2560*2  = 10,485,760
  f16* x1s = (f16*)(ws + 22282240);     // 2048*32*64*2  =  8,388,608
  f16* y2s = (f16*)(ws + 30670848);     // 2048*32*64*2  =  8,388,608

  prep<<<3080, 256, 0, stream>>>(x, W0, W1, xt, W0p, W1p, out);
  cin_fused<<<512, 256, 0, stream>>>(xt, W0p, W1p, b0v, b1v, x1s, y2s);
  finalize<<<2048, 128, 0, stream>>>(x1s, y2s, out);
}

// Round 14
// 59.975 us; speedup vs baseline: 1.0076x; 1.0076x over previous
//
#include <hip/hip_runtime.h>

typedef unsigned int   u32;
typedef unsigned short u16;
typedef _Float16       f16;

using f16x8  = __attribute__((ext_vector_type(8)))  _Float16;
using f16x4  = __attribute__((ext_vector_type(4)))  _Float16;
using f32x16 = __attribute__((ext_vector_type(16))) float;

#define LLDS16(G, L) __builtin_amdgcn_global_load_lds( \
  (const __attribute__((address_space(1))) u32*)(G), \
  (__attribute__((address_space(3))) u32*)(L), 16, 0, 0)

#define WAITV(N) { asm volatile("s_waitcnt vmcnt(" #N ")" ::: "memory"); \
                   __builtin_amdgcn_sched_barrier(0); }
#define FENCE_BAR() { asm volatile("s_waitcnt lgkmcnt(0)" ::: "memory"); \
                      __builtin_amdgcn_sched_barrier(0); \
                      __builtin_amdgcn_s_barrier(); \
                      __builtin_amdgcn_sched_barrier(0); }
#define BAR() { __builtin_amdgcn_s_barrier(); __builtin_amdgcn_sched_barrier(0); }
#define KEEP(x) asm volatile("" : "+v"(x))

// ---- merged prep: [bid<2560] x transpose+sums; [else] W0/W1 k-panel ----
__global__ __launch_bounds__(256)
void prep(const float* __restrict__ x,
          const float* __restrict__ W0, const float* __restrict__ W1,
          f16* __restrict__ xt, f16* __restrict__ W0p, f16* __restrict__ W1p,
          float* __restrict__ out){
  __shared__ char shm[33920];
  const int tid = threadIdx.x;
  if (blockIdx.x < 2560){
    float (*tile)[33] = (float(*)[33])shm;
    const int r0 = blockIdx.x << 5;
    const int c  = tid & 31;
    const int rp = tid >> 5;
#pragma unroll
    for (int p = 0; p < 4; ++p){
      const int r = (p << 3) + rp;
      float v = x[(size_t)(r0 + r) * 32 + c];
      tile[r][c] = v;
      float s = v;
#pragma unroll
      for (int off = 16; off > 0; off >>= 1) s += __shfl_xor(s, off, 32);
      if (c == 0){
        const int row = r0 + r;            // = b*40 + f
        out[(size_t)(row / 40) * 168 + (row % 40)] = s;
      }
    }
    __syncthreads();
#pragma unroll
    for (int p = 0; p < 4; ++p){
      const int dd = (p << 3) + rp;
      xt[(size_t)dd * 81920 + r0 + c] = (f16)tile[c][dd];
    }
  } else {
    u16* t = (u16*)shm;
    int kb = blockIdx.x - 2560;
    const float* in; f16* outp; int K;
    if (kb < 200){ in = W0; outp = W0p; K = 1600; }
    else         { kb -= 200; in = W1; outp = W1p; K = 2560; }
    const int kbase = kb << 3;
#pragma unroll 4
    for (int i = 0; i < 64; ++i){
      const int idx = tid + (i << 8);
      const int o   = idx >> 8;
      const int rem = idx & 255;
      const int e   = rem >> 5;
      const int dd  = rem & 31;
      const float v = in[(size_t)o * (K * 32) + (size_t)(kbase + e) * 32 + dd];
      union { f16 h; u16 u; } cv; cv.h = (f16)v;
      t[dd * 530 + o * 8 + e] = cv.u;
    }
    __syncthreads();
    const u32* t32 = (const u32*)t;
    u32* o32 = (u32*)outp;
    const int obase = kb << 8;
#pragma unroll 4
    for (int i = 0; i < 32; ++i){
      const int idx = tid + (i << 8);
      const int dd  = idx >> 8;
      const int rem = idx & 255;
      o32[(size_t)dd * (K * 32) + obase + rem] = t32[dd * 265 + rem];
    }
  }
}

// ---- fused CIN: 32x32x16, 64-row waves, triple-buffered B, 1 barrier/tile ----
// Block: 128 rows x 64 cols x one d, 4 waves (2 rowhalves x 2 colhalves).
// BK=160; 26 tiles (10 W0 + 16 W1); 2-deep prefetch, counted vmcnt(5).
// Per-tile: WAITV -> BAR -> ISSUE(t+2) -> [hoist all 10 B-frags, 1 lgkm wait]
// -> pk_mul+MFMA.  4 indep acc chains.
__global__ __launch_bounds__(256, 2)
void cin_fused(const f16* __restrict__ xt,     // [32][2048*40] f16
               const f16* __restrict__ W0p,    // [32][200][64][8] f16
               const f16* __restrict__ W1p,    // [32][320][64][8] f16
               const float* __restrict__ b0v, const float* __restrict__ b1v,
               f16* __restrict__ x1s,          // [2048][32][64] f16
               f16* __restrict__ y2s){         // [2048][32][64] f16
  constexpr int XOFF = 61440;           // after 3 x 20KB B bufs; x0/x1/y overlay
  constexpr int X0MS = 32 * 96;         // strip stride (x0)
  constexpr int X1MS = 32 * 144;        // strip stride (x1)

  const int bid = blockIdx.x;
  const int d   = ((bid & 7) << 2) | ((bid >> 3) & 3);   // XCD-local d groups
  const int b0  = (bid >> 5) << 7;      // 16 b-tiles of 128 rows
  const int tid = threadIdx.x;
  const int wv  = tid >> 6;
  const int wr  = wv >> 1;              // row half (64 rows)
  const int wc  = wv & 1;               // col half (32 cols)
  const int l   = tid & 63;
  const int hi  = l >> 5;               // k-run half
  const int lr  = l & 31;

  __shared__ char smem[79872];

  const f16* gW0 = W0p + (size_t)d * 102400;
  const f16* gW1 = W1p + (size_t)d * 163840;

  // W tile = 20480B = 20 x 1KB chunks; wave wv loads chunks {wv+4j}, 5 each.
#define ISSUE(I, BUF) do { \
    const f16* src_ = ((I) < 10) ? (gW0 + (size_t)(I) * 10240) \
                                 : (gW1 + (size_t)((I) - 10) * 10240); \
    const f16* gt_ = src_ + l * 8; \
    char* lb_ = smem + (BUF) * 20480; \
    _Pragma("unroll") \
    for (int j_ = 0; j_ < 5; ++j_) \
      LLDS16(gt_ + (size_t)(wv + 4 * j_) * 512, lb_ + (wv + 4 * j_) * 1024); \
  } while (0)

  ISSUE(0, 0);
  ISSUE(1, 1);

  { // stage x0 tile: 128 rows * 80B -> stride 96B
    const uint4* src = (const uint4*)(xt + (size_t)d * 81920 + (size_t)b0 * 40);
#pragma unroll
    for (int it = 0; it < 3; ++it){
      const int idx = tid + (it << 8);
      if (idx < 640){
        const int r = idx / 5, c = idx - r * 5;
        *(uint4*)(smem + XOFF + r * 96 + c * 16) = src[idx];
      }
    }
  }
  __syncthreads();                      // drains vmcnt: tiles 0,1 + x0 landed

  const char* x0r = smem + XOFF + ((wr << 6) + lr) * 96;
  const char* x1r = smem + XOFF + ((wr << 6) + lr) * 144;
  const int   col = (wc << 5) + lr;
  const float bv1 = b0v[col];
  const float bv2 = b1v[col];

  // sl[m][s] = x0 f-block (s+hi)%5 of strip-m row (pinned in VGPRs)
  f16x8 sl[2][5];
#pragma unroll
  for (int m = 0; m < 2; ++m){
    const char* xe = x0r + m * X0MS + hi * 16;
#pragma unroll
    for (int t = 0; t < 4; ++t) sl[m][t] = *(const f16x8*)(xe + t * 16);
    sl[m][4] = *(const f16x8*)(x0r + m * X0MS + (hi ? 0 : 64));
  }
  KEEP(sl[0][0]); KEEP(sl[0][1]); KEEP(sl[0][2]); KEEP(sl[0][3]); KEEP(sl[0][4]);
  KEEP(sl[1][0]); KEEP(sl[1][1]); KEEP(sl[1][2]); KEEP(sl[1][3]); KEEP(sl[1][4]);

  const f32x16 fz = {0,0,0,0,0,0,0,0,0,0,0,0,0,0,0,0};
  f32x16 acc0a = fz, acc0b = fz, acc1a = fz, acc1b = fz;   // 4 indep chains

  const int vb = (hi << 10) + (wc << 9) + (lr << 4);

  // r8 = si*4 + 2p + hi; slot = (si*4+2p)%5 (hi-rotated sl); h-elem tables
  static constexpr int J0[5]  = {0, 4, 3, 2, 1};
  static constexpr int H0[5]  = {0, 0, 1, 2, 3};
  static constexpr int H0b[5] = {0, 1, 1, 2, 3};
  static constexpr int S0[5]  = {0, 1, 0, 0, 0};
  static constexpr int J2[5]  = {2, 1, 0, 4, 3};
  static constexpr int H2[5]  = {0, 1, 2, 2, 3};
  static constexpr int H2b[5] = {0, 1, 2, 3, 3};
  static constexpr int S2[5]  = {0, 0, 0, 1, 0};

  // All 10 B-frags hoisted into registers, ONE lgkm wait, then pure MFMA+VALU.
#define COMP(BB) do { \
  f16x8 Bf0, Bf1, Bf2, Bf3, Bf4, Bf5, Bf6, Bf7, Bf8, Bf9; \
  Bf0 = *(const f16x8*)((BB) + vb);           \
  Bf1 = *(const f16x8*)((BB) + vb + 2048);    \
  Bf2 = *(const f16x8*)((BB) + vb + 4096);    \
  Bf3 = *(const f16x8*)((BB) + vb + 6144);    \
  Bf4 = *(const f16x8*)((BB) + vb + 8192);    \
  Bf5 = *(const f16x8*)((BB) + vb + 10240);   \
  Bf6 = *(const f16x8*)((BB) + vb + 12288);   \
  Bf7 = *(const f16x8*)((BB) + vb + 14336);   \
  Bf8 = *(const f16x8*)((BB) + vb + 16384);   \
  Bf9 = *(const f16x8*)((BB) + vb + 18432);   \
  asm volatile("s_waitcnt lgkmcnt(0)" ::: "memory"); \
  __builtin_amdgcn_sched_barrier(0); \
  __builtin_amdgcn_s_setprio(1); \
  _Pragma("unroll") \
  for (int si = 0; si < 5; ++si){ \
    const f16x8 bf0 = (si == 0) ? Bf0 : (si == 1) ? Bf2 : (si == 2) ? Bf4 : (si == 3) ? Bf6 : Bf8; \
    const f16x8 bf2 = (si == 0) ? Bf1 : (si == 1) ? Bf3 : (si == 2) ? Bf5 : (si == 3) ? Bf7 : Bf9; \
    const f16 xa00 = (S0[si] && hi) ? xh0[H0b[si]] : xh0[H0[si]]; \
    const f16 xa01 = (S0[si] && hi) ? xh1[H0b[si]] : xh1[H0[si]]; \
    const f16 xa20 = (S2[si] && hi) ? xh0[H2b[si]] : xh0[H2[si]]; \
    const f16 xa21 = (S2[si] && hi) ? xh1[H2b[si]] : xh1[H2[si]]; \
    acc0a = __builtin_amdgcn_mfma_f32_32x32x16_f16(sl[0][J0[si]] * xa00, bf0, acc0a, 0, 0, 0); \
    acc1a = __builtin_amdgcn_mfma_f32_32x32x16_f16(sl[1][J0[si]] * xa01, bf0, acc1a, 0, 0, 0); \
    acc0b = __builtin_amdgcn_mfma_f32_32x32x16_f16(sl[0][J2[si]] * xa20, bf2, acc0b, 0, 0, 0); \
    acc1b = __builtin_amdgcn_mfma_f32_32x32x16_f16(sl[1][J2[si]] * xa21, bf2, acc1b, 0, 0, 0); \
  } \
  __builtin_amdgcn_s_setprio(0); \
} while (0)

  int cur = 0, ib = 2;

  // ---------------- phase 1: xk = x0, tiles 0..9 ----------------
  for (int t = 0; t < 10; ++t){
    if (t > 0){ WAITV(5); BAR(); }      // tile t landed (all waves after BAR)
    ISSUE(t + 2, ib);                   // tiles 2..11 (10,11 are W1 tiles 0,1)
    const f16x4 xh0 = *(const f16x4*)(x0r + t * 8);
    const f16x4 xh1 = *(const f16x4*)(x0r + X0MS + t * 8);
    COMP(smem + cur * 20480);
    cur = cur + 1; if (cur == 3) cur = 0;
    ib  = ib + 1;  if (ib == 3)  ib = 0;
  }

  // ---- epilogue 1: x1 -> LDS (overlay x0), coalesced partial store ----
  {
    FENCE_BAR();                        // all waves done COMP(9)/x0 reads
    u16* x1w = (u16*)(smem + XOFF);
#pragma unroll
    for (int m = 0; m < 2; ++m)
#pragma unroll
      for (int reg = 0; reg < 16; ++reg){
        const int row = (wr << 6) + (m << 5) + (reg & 3) + ((reg >> 2) << 3) + (hi << 2);
        float v = (m ? acc1a[reg] + acc1b[reg] : acc0a[reg] + acc0b[reg]) + bv1;
        v = v > 0.f ? v : 0.f;
        union { f16 h; u16 u; } cv; cv.h = (f16)v;
        x1w[row * 72 + col] = cv.u;
      }
    acc0a = fz; acc0b = fz; acc1a = fz; acc1b = fz;
    FENCE_BAR();                        // x1 tile visible to all waves
#pragma unroll
    for (int it = 0; it < 4; ++it){     // 4 global stores (counted in vmcnt)
      const int u   = tid + (it << 8);
      const int row = u >> 3, ch = u & 7;
      const f16x8 vv = *(const f16x8*)((const char*)x1w + row * 144 + ch * 16);
      *(f16x8*)(x1s + (size_t)(b0 + row) * 2048 + d * 64 + ch * 8) = vv;
    }
  }

  // ---------------- phase 2: xk = x1 (LDS), tiles 10..25 ----------------
  for (int t2 = 0; t2 < 16; ++t2){
    if (t2 < 2)       { WAITV(9); }     // tile landed past 4 stores + 5 chunks
    else if (t2 < 15) { WAITV(5); }
    else              { WAITV(0); }
    BAR();
    if (t2 + 2 < 16) ISSUE(12 + t2, ib);
    const f16x4 xh0 = *(const f16x4*)(x1r + t2 * 8);
    const f16x4 xh1 = *(const f16x4*)(x1r + X1MS + t2 * 8);
    COMP(smem + cur * 20480);
    cur = cur + 1; if (cur == 3) cur = 0;
    ib  = ib + 1;  if (ib == 3)  ib = 0;
  }

  // ---- epilogue 2: y2 -> LDS (overlay x1) -> coalesced partial store ----
  {
    FENCE_BAR();                        // all waves done phase-2 x1 reads
    u16* yw = (u16*)(smem + XOFF);
#pragma unroll
    for (int m = 0; m < 2; ++m)
#pragma unroll
      for (int reg = 0; reg < 16; ++reg){
        const int row = (wr << 6) + (m << 5) + (reg & 3) + ((reg >> 2) << 3) + (hi << 2);
        float v = (m ? acc1a[reg] + acc1b[reg] : acc0a[reg] + acc0b[reg]) + bv2;
        v = v > 0.f ? v : 0.f;
        union { f16 h; u16 u; } cv; cv.h = (f16)v;
        yw[row * 72 + col] = cv.u;
      }
    FENCE_BAR();
#pragma unroll
    for (int it = 0; it < 4; ++it){
      const int u   = tid + (it << 8);
      const int row = u >> 3, ch = u & 7;
      const f16x8 vv = *(const f16x8*)((const char*)yw + row * 144 + ch * 16);
      *(f16x8*)(y2s + (size_t)(b0 + row) * 2048 + d * 64 + ch * 8) = vv;
    }
  }
#undef ISSUE
#undef COMP
}

// ------- final: out[b, 40:168] = sum_d concat(x1, y2), coalesced reads -------
__global__ __launch_bounds__(128)
void finalize(const f16* __restrict__ x1s, const f16* __restrict__ y2s,
              float* __restrict__ out){
  const int b = blockIdx.x;
  const int t = threadIdx.x;
  if (t < 64){
    float s = 0.f;
#pragma unroll
    for (int d = 0; d < 32; ++d) s += (float)x1s[(size_t)b * 2048 + d * 64 + t];
    out[(size_t)b * 168 + 40 + t] = s;
  } else {
    const int o = t - 64;
    float s = 0.f;
#pragma unroll
    for (int d = 0; d < 32; ++d) s += (float)y2s[(size_t)b * 2048 + d * 64 + o];
    out[(size_t)b * 168 + 104 + o] = s;
  }
}

extern "C" void kernel_launch(void* const* d_in, const int* in_sizes, int n_in,
                              void* d_out, int out_size, void* d_ws, size_t ws_size,
                              hipStream_t stream){
  const float* x   = (const float*)d_in[0];
  const float* W0  = (const float*)d_in[1];
  const float* b0v = (const float*)d_in[2];
  const float* W1  = (const float*)d_in[3];
  const float* b1v = (const float*)d_in[4];
  float* out = (float*)d_out;

  char* ws = (char*)d_ws;
  f16* xt  = (f16*)(ws + 0);            // 32*2048*40*2  =  5,242,880
  f16* W0p = (f16*)(ws + 5242880);      // 32*64*1600*2  =  6,553,600
  f16* W1p = (f16*)(ws + 11796480);     // 32*64*2560*2  = 10,485,760
  f16* x1s = (f16*)(ws + 22282240);     // 2048*32*64*2  =  8,388,608
  f16* y2s = (f16*)(ws + 30670848);     // 2048*32*64*2  =  8,388,608

  prep<<<3080, 256, 0, stream>>>(x, W0, W1, xt, W0p, W1p, out);
  cin_fused<<<512, 256, 0, stream>>>(xt, W0p, W1p, b0v, b1v, x1s, y2s);
  finalize<<<2048, 128, 0, stream>>>(x1s, y2s, out);
}